// Round 14
// baseline (29.722 us; speedup 1.0000x reference)
//
#include <hip/hip_runtime.h>

// PositionLossVal: offset [4,18,512,512] f32, optical_flow [4,8,512,512] f32 -> scalar f32.
// Per pixel: x=off[i], y=off[i+9] (i<9); u=flow[j], v=flow[j+1] (j<4).
// md = inside ? perp : min(d1,d2); min over j, mean over i, sum over b,h,w, /(h*w).
//
// Ledger: R5 2048 same-address atomic tail +60us (8 is fine — serialization ~100cyc each).
// PPT=4 => 180 VGPR, dead (R1/R7). __launch_bounds__ min-waves arg => hipcc targets
// half the implied VGPR cap and force-spills 100-160MB (R4/R8/R9) — never pass it.
// R10 global_load_lds tile: stage->drain serialization +6us. R2/R3/R6/R11 structure-
// invariant 26.7-28.4us. R12 packed-f32 -1.6us. R13 Lagrange+min3 trim -0.3us => 24.8us.
// R14: 8-block reduce with one atomicAdd(out) each (tail ~2.5us -> ~1us); out zeroed
// by a 4-byte memset node per call. Main kernel = R13 body unchanged.

#define HW_BITS 18
#define HW_ (1 << HW_BITS)          // 512*512
#define NOFF 9
#define NFLOW 4
#define NPIX (4 * HW_)              // 1,048,576 pixels
#define PPT 2                       // pixel pair in the two halves of a v2f
#define BLK 256
#define GRID1 (NPIX / PPT / BLK)    // 2048 blocks
#define NPART (GRID1 * (BLK / 64))  // 8192 wave partials (32 KB)
#define RBLK 256
#define RGRID 8                     // 8 blocks x 1024 partials each

typedef float v2f __attribute__((ext_vector_type(2)));

__global__ __launch_bounds__(BLK)   // block size only — min-waves arg is poison (ledger)
void pos_loss_main(const float* __restrict__ off, const float* __restrict__ flow,
                   float* __restrict__ partial)
{
    const int t  = blockIdx.x * BLK + threadIdx.x;
    const int g  = t * PPT;                          // 2 consecutive pixels, same image
    const int b  = g >> HW_BITS;
    const int hw = g & (HW_ - 1);
    const float* offb = off  + ((size_t)b * (2 * NOFF)) * HW_ + hw;
    const float* flb  = flow + ((size_t)b * 8) * HW_ + hw;

    // All 23 vec2 loads issued before first use.
    v2f f2[NFLOW + 1];
#pragma unroll
    for (int j = 0; j <= NFLOW; ++j)
        f2[j] = *reinterpret_cast<const v2f*>(flb + (size_t)j * HW_);
    v2f xs2[NOFF], ys2[NOFF];
#pragma unroll
    for (int i = 0; i < NOFF; ++i) {
        xs2[i] = *reinterpret_cast<const v2f*>(offb + (size_t)i * HW_);
        ys2[i] = *reinterpret_cast<const v2f*>(offb + (size_t)(i + NOFF) * HW_);
    }

    // Per-j invariants: uu = u^2+v^2, r = 1/uu.
    v2f uu_[NFLOW], r_[NFLOW];
#pragma unroll
    for (int j = 0; j < NFLOW; ++j) {
        const v2f u = f2[j], v = f2[j + 1];
        const v2f uu = u * u + v * v;
        uu_[j] = uu;
        r_[j].x = __builtin_amdgcn_rcpf(uu.x);
        r_[j].y = __builtin_amdgcn_rcpf(uu.y);
    }

    v2f acc = {0.f, 0.f};
#pragma unroll
    for (int i = 0; i < NOFF; ++i) {
        const v2f x  = xs2[i], y = ys2[i];
        const v2f x2 = x * x;
        const v2f d1sq = y * y + x2;
        v2f m2 = {1e30f, 1e30f};
#pragma unroll
        for (int j = 0; j < NFLOW; ++j) {
            const v2f u = f2[j], v = f2[j + 1];
            const v2f uu = uu_[j];
            // Packed portion (9 v_pk_* ops):
            const v2f proj = x * u + y * v;                  // mul + fma
            const v2f p2   = d1sq - (proj * proj) * r_[j];   // mul + fma (Lagrange)
            const v2f d1uu = d1sq + uu;
            const v2f d2sq = d1uu - 2.0f * proj;             // fma
            const v2f w    = v * y + x2;                     // fma
            const v2f ins  = w * (w - uu);                   // sub + mul
            // Scalar tail (3 ops/px): cmp+cndmask, min3 chain.
            const float selx = (ins.x <= 0.f) ? p2.x : d1sq.x;
            const float sely = (ins.y <= 0.f) ? p2.y : d1sq.y;
            m2.x = fminf(fminf(m2.x, d2sq.x), selx);
            m2.y = fminf(fminf(m2.y, d2sq.y), sely);
        }
        acc.x += __builtin_amdgcn_sqrtf(fmaxf(m2.x, 0.f));
        acc.y += __builtin_amdgcn_sqrtf(fmaxf(m2.y, 0.f));
    }
    float a = acc.x + acc.y;

    // Per-wave shuffle reduce; no barrier — waves retire independently.
#pragma unroll
    for (int o = 32; o > 0; o >>= 1) a += __shfl_down(a, o, 64);
    if ((threadIdx.x & 63) == 0)
        partial[blockIdx.x * (BLK / 64) + (threadIdx.x >> 6)] = a;
}

__global__ __launch_bounds__(RBLK)
void pos_loss_reduce(const float* __restrict__ partial, float* __restrict__ out)
{
    // 8 blocks x 1024 partials: 4 coalesced loads/thread, block-reduce, one
    // device-scope atomicAdd per block (8 total — negligible serialization).
    const int base = blockIdx.x * (NPART / RGRID) + (int)threadIdx.x;
    float s = 0.f;
#pragma unroll
    for (int k = 0; k < NPART / RGRID / RBLK; ++k)   // 4 loads
        s += partial[base + k * RBLK];
#pragma unroll
    for (int o = 32; o > 0; o >>= 1) s += __shfl_down(s, o, 64);
    __shared__ float sm[RBLK / 64];
    const int lane = threadIdx.x & 63, wid = threadIdx.x >> 6;
    if (lane == 0) sm[wid] = s;
    __syncthreads();
    if (threadIdx.x == 0)
        atomicAdd(out, (sm[0] + sm[1] + sm[2] + sm[3]) * (1.0f / (9.0f * (float)HW_)));
}

extern "C" void kernel_launch(void* const* d_in, const int* in_sizes, int n_in,
                              void* d_out, int out_size, void* d_ws, size_t ws_size,
                              hipStream_t stream) {
    const float* offset = (const float*)d_in[0];   // [4,18,512,512]
    const float* flow   = (const float*)d_in[1];   // [4,8,512,512]
    float* partial = (float*)d_ws;                 // NPART floats (32 KB), fully rewritten
    float* out     = (float*)d_out;                // 1 float, zeroed per call below

    hipMemsetAsync(out, 0, sizeof(float), stream); // capture-safe memset node
    pos_loss_main<<<GRID1, BLK, 0, stream>>>(offset, flow, partial);
    pos_loss_reduce<<<RGRID, RBLK, 0, stream>>>(partial, out);
}

// Round 15
// 23.943 us; speedup vs baseline: 1.2414x; 1.2414x over previous
//
#include <hip/hip_runtime.h>

// PositionLossVal: offset [4,18,512,512] f32, optical_flow [4,8,512,512] f32 -> scalar f32.
// Per pixel: x=off[i], y=off[i+9] (i<9); u=flow[j], v=flow[j+1] (j<4).
// md = inside ? perp : min(d1,d2); min over j, mean over i, sum over b,h,w, /(h*w).
//
// Ledger (what moved / what didn't):
//  R5: 2048 same-address device atomics serialize at the cross-XCD coherence point (+60us).
//  R1/R7: PPT=4 => 180 VGPR, 2 waves/SIMD — dead.
//  R4/R8/R9: __launch_bounds__(256,N) min-waves arg makes hipcc target (512/N)/2 VGPRs
//    and force-spill 100-160MB scratch — never pass it.
//  R10: global_load_lds tile => stage->vmcnt(0)->compute serialization, +6us.
//  R2/R3/R6/R11: occupancy/bytes-in-flight/reduction-shape/load-placement all null (26.7-28.4).
//  R12: VOP3P packed-f32 (pixel pair in v2f halves) -1.6us.
//  R13: Lagrange proj-sharing + min3 tail + clamp -0.3us => 24.78us. BEST.
//  R14: per-call 4-byte hipMemsetAsync node costs ~5us in graph replay (+atomic tail) — revert.
// R15 = R13 exact revert. Main kernel at composite floor (47MB forced HBM re-fetch between
// replays + L3 remainder + ~5us packed VALU); tail ~2-3us irreducible without node overhead.

#define HW_BITS 18
#define HW_ (1 << HW_BITS)          // 512*512
#define NOFF 9
#define NFLOW 4
#define NPIX (4 * HW_)              // 1,048,576 pixels
#define PPT 2                       // pixel pair in the two halves of a v2f
#define BLK 256
#define GRID1 (NPIX / PPT / BLK)    // 2048 blocks
#define NPART (GRID1 * (BLK / 64))  // 8192 wave partials (32 KB)
#define RBLK 1024

typedef float v2f __attribute__((ext_vector_type(2)));

__global__ __launch_bounds__(BLK)   // block size only — min-waves arg is poison (ledger)
void pos_loss_main(const float* __restrict__ off, const float* __restrict__ flow,
                   float* __restrict__ partial)
{
    const int t  = blockIdx.x * BLK + threadIdx.x;
    const int g  = t * PPT;                          // 2 consecutive pixels, same image
    const int b  = g >> HW_BITS;
    const int hw = g & (HW_ - 1);
    const float* offb = off  + ((size_t)b * (2 * NOFF)) * HW_ + hw;
    const float* flb  = flow + ((size_t)b * 8) * HW_ + hw;

    // All 23 vec2 loads issued before first use.
    v2f f2[NFLOW + 1];
#pragma unroll
    for (int j = 0; j <= NFLOW; ++j)
        f2[j] = *reinterpret_cast<const v2f*>(flb + (size_t)j * HW_);
    v2f xs2[NOFF], ys2[NOFF];
#pragma unroll
    for (int i = 0; i < NOFF; ++i) {
        xs2[i] = *reinterpret_cast<const v2f*>(offb + (size_t)i * HW_);
        ys2[i] = *reinterpret_cast<const v2f*>(offb + (size_t)(i + NOFF) * HW_);
    }

    // Per-j invariants: uu = u^2+v^2, r = 1/uu.
    v2f uu_[NFLOW], r_[NFLOW];
#pragma unroll
    for (int j = 0; j < NFLOW; ++j) {
        const v2f u = f2[j], v = f2[j + 1];
        const v2f uu = u * u + v * v;
        uu_[j] = uu;
        r_[j].x = __builtin_amdgcn_rcpf(uu.x);
        r_[j].y = __builtin_amdgcn_rcpf(uu.y);
    }

    v2f acc = {0.f, 0.f};
#pragma unroll
    for (int i = 0; i < NOFF; ++i) {
        const v2f x  = xs2[i], y = ys2[i];
        const v2f x2 = x * x;
        const v2f d1sq = y * y + x2;
        v2f m2 = {1e30f, 1e30f};
#pragma unroll
        for (int j = 0; j < NFLOW; ++j) {
            const v2f u = f2[j], v = f2[j + 1];
            const v2f uu = uu_[j];
            // Packed portion (9 v_pk_* ops):
            const v2f proj = x * u + y * v;                  // mul + fma
            const v2f p2   = d1sq - (proj * proj) * r_[j];   // mul + fma (Lagrange)
            const v2f d1uu = d1sq + uu;
            const v2f d2sq = d1uu - 2.0f * proj;             // fma
            const v2f w    = v * y + x2;                     // fma
            const v2f ins  = w * (w - uu);                   // sub + mul
            // Scalar tail (3 ops/px): cmp+cndmask, min3 chain.
            const float selx = (ins.x <= 0.f) ? p2.x : d1sq.x;
            const float sely = (ins.y <= 0.f) ? p2.y : d1sq.y;
            m2.x = fminf(fminf(m2.x, d2sq.x), selx);
            m2.y = fminf(fminf(m2.y, d2sq.y), sely);
        }
        acc.x += __builtin_amdgcn_sqrtf(fmaxf(m2.x, 0.f));
        acc.y += __builtin_amdgcn_sqrtf(fmaxf(m2.y, 0.f));
    }
    float a = acc.x + acc.y;

    // Per-wave shuffle reduce; no barrier — waves retire independently.
#pragma unroll
    for (int o = 32; o > 0; o >>= 1) a += __shfl_down(a, o, 64);
    if ((threadIdx.x & 63) == 0)
        partial[blockIdx.x * (BLK / 64) + (threadIdx.x >> 6)] = a;
}

__global__ __launch_bounds__(RBLK)
void pos_loss_reduce(const float* __restrict__ partial, float* __restrict__ out)
{
    float s = 0.f;
#pragma unroll
    for (int k = 0; k < NPART / RBLK; ++k)          // 8 coalesced loads
        s += partial[k * RBLK + (int)threadIdx.x];
#pragma unroll
    for (int o = 32; o > 0; o >>= 1) s += __shfl_down(s, o, 64);
    __shared__ float sm[RBLK / 64];                 // 16 wave sums
    const int lane = threadIdx.x & 63, wid = threadIdx.x >> 6;
    if (lane == 0) sm[wid] = s;
    __syncthreads();
    if (wid == 0) {
        float v = (lane < RBLK / 64) ? sm[lane] : 0.f;
#pragma unroll
        for (int o = 8; o > 0; o >>= 1) v += __shfl_down(v, o, 64);
        if (lane == 0)
            out[0] = v * (1.0f / (9.0f * (float)HW_));
    }
}

extern "C" void kernel_launch(void* const* d_in, const int* in_sizes, int n_in,
                              void* d_out, int out_size, void* d_ws, size_t ws_size,
                              hipStream_t stream) {
    const float* offset = (const float*)d_in[0];   // [4,18,512,512]
    const float* flow   = (const float*)d_in[1];   // [4,8,512,512]
    float* partial = (float*)d_ws;                 // NPART floats (32 KB), fully rewritten
    float* out     = (float*)d_out;                // 1 float

    pos_loss_main<<<GRID1, BLK, 0, stream>>>(offset, flow, partial);
    pos_loss_reduce<<<1, RBLK, 0, stream>>>(partial, out);
}